// Round 3
// baseline (387.093 us; speedup 1.0000x reference)
//
#include <hip/hip_runtime.h>
#include <hip/hip_bf16.h>

// EmbedLayerUpdate, round 3.
// pre = W @ mu + b per batch ([4096,K]x[K,64]), fused relu-block epilogue.
// A (W fp32) read direct global->reg in MFMA fragment order (no LDS, no prepass).
// B (mu) pre-transposed bf16 swizzled tiles in ws; global_load_lds + 3-deep bufs,
// counted vmcnt, raw s_barrier. XCD-bijective block swizzle. B=16, P=64.

#define DOUT 4096
typedef __bf16 bf16x8 __attribute__((ext_vector_type(8)));
typedef float  f32x4  __attribute__((ext_vector_type(4)));
typedef unsigned int u32;

__device__ __forceinline__ __bf16 bfc(float x) { return (__bf16)x; }

__device__ __forceinline__ bf16x8 cvt8(const float4 a, const float4 b) {
    bf16x8 r;
    r[0]=bfc(a.x); r[1]=bfc(a.y); r[2]=bfc(a.z); r[3]=bfc(a.w);
    r[4]=bfc(b.x); r[5]=bfc(b.y); r[6]=bfc(b.z); r[7]=bfc(b.w);
    return r;
}

__device__ __forceinline__ void gl_lds16(const void* g, void* l) {
    __builtin_amdgcn_global_load_lds(
        (const __attribute__((address_space(1))) u32*)g,
        (__attribute__((address_space(3))) u32*)l, 16, 0, 0);
}

// 128-byte rows (64 bf16): XOR-swizzle 16B chunks with row&7
__device__ __forceinline__ int aoff(int r, int c16) {
    return (r << 7) + ((c16 << 4) ^ ((r & 7) << 4));
}
// 256-byte rows (128 bf16): XOR-swizzle with row&15
__device__ __forceinline__ int eoff(int r, int byteoff) {
    return (r << 8) + (byteoff ^ ((r & 15) << 4));
}
// B-tile read: [p][swz k] rows of 128B
__device__ __forceinline__ int boff(int p, int kbyte) {
    return (p << 7) + (kbyte ^ ((p & 7) << 4));
}

#define WS_MU0 0
#define WS_MU1 (4u << 20)
#define WS_SM  (12u << 20)

#define BAR() asm volatile("s_barrier" ::: "memory")

// ---------------- prepass: mu0 -> bf16 transposed swizzled tiles; small weights -> bf16 ----------------
__global__ __launch_bounds__(256)
void prepass_kernel(const float* __restrict__ mu0, const float* __restrict__ fc11W,
                    const float* __restrict__ fc2W, const float* __restrict__ fc21W,
                    char* __restrict__ ws)
{
    const int blk = blockIdx.x, t = threadIdx.x;
    if (blk < 512) {                       // mu0t: [b 16][kt 32] tiles of [p 64][swz 64k]
        const int b = blk >> 5, kt = blk & 31;
        const int p = t & 63, kc = t >> 6; // kc in 0..3, 16 k each
        const float* src = mu0 + ((size_t)b * 2048 + kt * 64 + kc * 16) * 64 + p;
        char* tile = ws + WS_MU0 + ((size_t)b * 32 + kt) * 8192;
        float v[16];
        #pragma unroll
        for (int i = 0; i < 16; ++i) v[i] = src[(size_t)i * 64];
        bf16x8 o0, o1;
        #pragma unroll
        for (int i = 0; i < 8; ++i) { o0[i] = bfc(v[i]); o1[i] = bfc(v[8 + i]); }
        const int c0 = (kc * 2) ^ (p & 7), c1 = (kc * 2 + 1) ^ (p & 7);
        *(bf16x8*)(tile + p * 128 + c0 * 16) = o0;
        *(bf16x8*)(tile + p * 128 + c1 * 16) = o1;
    } else {                               // small weights: fc11 | fc2 | fc21 (bf16)
        const int idx = (blk - 512) * 256 + t;
        __bf16* dst = (__bf16*)(ws + WS_SM);
        if (idx < 4096)        dst[idx] = bfc(fc11W[idx]);
        else if (idx < 12288)  dst[idx] = bfc(fc2W[idx - 4096]);
        else                   dst[idx] = bfc(fc21W[idx - 12288]);
    }
}

// ---------------- layer kernel ----------------
template <int K, bool WRITE_T>
__global__ __launch_bounds__(256, 2)
void layer_kernel(const float* __restrict__ W, const float* __restrict__ bias,
                  const char* __restrict__ wsB,      // bf16 transposed swizzled mu tiles
                  const float* __restrict__ lb, const float* __restrict__ ub,
                  const float* __restrict__ ps, const float* __restrict__ ss,
                  const float* __restrict__ mask,
                  const float* __restrict__ fc1W, const float* __restrict__ fc1b,
                  const __bf16* __restrict__ fc11bf, const float* __restrict__ fc11b,
                  const __bf16* __restrict__ fc2bf, const float* __restrict__ fc2b,
                  const __bf16* __restrict__ fc21bf, const float* __restrict__ fc21b,
                  float* __restrict__ out, char* __restrict__ wsT)
{
    constexpr int NT = K / 64;
    __shared__ __align__(16) char lds[65536];
    // main loop: B bufs at 0/8192/16384. epilogue: E at 0 (32K), T at 32768, U at 49152.
    char* const T_lds = lds + 32768;
    char* const U_lds = lds + 49152;

    const int tid = threadIdx.x;
    const int lane = tid & 63, wv = tid >> 6;
    const int wm = wv >> 1, wn = wv & 1;
    const int lr = lane & 15, lg = lane >> 4;

    // XCD-bijective swizzle: 512 = 8 xcd * 64; each XCD: 4 panels x 16 batches
    const int id = blockIdx.x;
    const int vid = (id & 7) * 64 + (id >> 3);
    const int panel = vid >> 4;
    const int b = vid & 15;
    const int orow0 = panel * 128;

    const float* wBase = W + ((size_t)(orow0 + wm * 64 + lr)) * K + lg * 8;
    const char*  bSrc  = wsB + ((size_t)b * NT) * 8192;

    const f32x4 z = {0.f, 0.f, 0.f, 0.f};
    f32x4 acc[4][2];
    #pragma unroll
    for (int m = 0; m < 4; ++m) { acc[m][0] = z; acc[m][1] = z; }

    float4 pa[2][4][2];
    bf16x8 aC[2][4];

    char* q0 = lds;
    char* q1 = lds + 8192;
    char* q2 = lds + 16384;

    // prologue: stage B(0), B(1); prefetch A(0)
    #pragma unroll
    for (int q = 0; q < 2; ++q) {
        gl_lds16(bSrc + (size_t)(wv * 128 + q * 64 + lane) * 16, q0 + (wv * 128 + q * 64) * 16);
        gl_lds16(bSrc + 8192 + (size_t)(wv * 128 + q * 64 + lane) * 16, q1 + (wv * 128 + q * 64) * 16);
    }
    #pragma unroll
    for (int ks = 0; ks < 2; ++ks)
        #pragma unroll
        for (int m = 0; m < 4; ++m) {
            const float* p = wBase + (size_t)m * (16 * K) + ks * 32;
            pa[ks][m][0] = *(const float4*)p;
            pa[ks][m][1] = *(const float4*)(p + 4);
        }

    for (int t = 0; t < NT; ++t) {
        // s1: convert prefetched A(t)  (compiler inserts vmcnt wait for pa)
        #pragma unroll
        for (int ks = 0; ks < 2; ++ks)
            #pragma unroll
            for (int m = 0; m < 4; ++m)
                aC[ks][m] = cvt8(pa[ks][m][0], pa[ks][m][1]);
        // s2: prefetch A(t+1)
        if (t + 1 < NT) {
            #pragma unroll
            for (int ks = 0; ks < 2; ++ks)
                #pragma unroll
                for (int m = 0; m < 4; ++m) {
                    const float* p = wBase + (size_t)m * (16 * K) + (t + 1) * 64 + ks * 32;
                    pa[ks][m][0] = *(const float4*)p;
                    pa[ks][m][1] = *(const float4*)(p + 4);
                }
        }
        // s3: stage B(t+2)
        if (t + 2 < NT) {
            const char* s = bSrc + (size_t)(t + 2) * 8192;
            #pragma unroll
            for (int q = 0; q < 2; ++q)
                gl_lds16(s + (size_t)(wv * 128 + q * 64 + lane) * 16, q2 + (wv * 128 + q * 64) * 16);
        }
        // s4: ensure B(t) landed (counted: keep newer loads in flight)
        if (t < NT - 2)      asm volatile("s_waitcnt vmcnt(36)" ::: "memory");
        else if (t == NT - 2) asm volatile("s_waitcnt vmcnt(34)" ::: "memory");
        else                 asm volatile("s_waitcnt vmcnt(16)" ::: "memory");
        BAR();
        // s5+s6: read B frags, MFMA
        #pragma unroll
        for (int ks = 0; ks < 2; ++ks) {
            bf16x8 bb[2];
            #pragma unroll
            for (int n = 0; n < 2; ++n)
                bb[n] = *(const bf16x8*)(q0 + boff(wn * 32 + n * 16 + lr, ks * 64 + lg * 16));
            #pragma unroll
            for (int m = 0; m < 4; ++m)
                #pragma unroll
                for (int n = 0; n < 2; ++n)
                    acc[m][n] = __builtin_amdgcn_mfma_f32_16x16x32_bf16(aC[ks][m], bb[n], acc[m][n], 0, 0, 0);
        }
        asm volatile("s_waitcnt lgkmcnt(0)" ::: "memory");
        BAR();
        char* tq = q0; q0 = q1; q1 = q2; q2 = tq;
    }
    __syncthreads();

    // ---------------- epilogue ----------------
    // T = relu(info @ fc1W^T + fc1b) -> T_lds ; pre+bias -> E cols 0..63
    {
        const int row = tid >> 1;
        const int j0 = (tid & 1) * 32;
        const int g = b * DOUT + orow0 + row;
        const float lv = lb[g], uv = ub[g];
        const float lt = fminf(lv, 0.f), ut = fmaxf(uv, 0.f);
        const float diff = ut - lt;
        const float urr = ut / (diff + 1e-8f);
        const float lrr = 1.f - urr, i3 = ps[g], i4 = ss[g];
        #pragma unroll
        for (int c = 0; c < 4; ++c) {
            bf16x8 v;
            #pragma unroll
            for (int jj = 0; jj < 8; ++jj) {
                const int j = j0 + c * 8 + jj;
                const float* w = fc1W + j * 5;
                const float tv = fc1b[j] + urr * w[0] + lrr * w[1] + diff * w[2]
                               + i3 * w[3] + i4 * w[4];
                v[jj] = bfc(fmaxf(tv, 0.f));
            }
            *(bf16x8*)(T_lds + aoff(row, (j0 >> 3) + c)) = v;
        }
    }
    #pragma unroll
    for (int m = 0; m < 4; ++m)
        #pragma unroll
        for (int n = 0; n < 2; ++n) {
            const int col = wn * 32 + n * 16 + lr;
            #pragma unroll
            for (int r = 0; r < 4; ++r) {
                const int row = wm * 64 + m * 16 + lg * 4 + r;
                const float bs = bias[orow0 + row];
                *(__bf16*)(lds + eoff(row, 2 * col)) = bfc(acc[m][n][r] + bs);
            }
        }
    __syncthreads();

    // H = T @ fc11W^T + fc11b -> E cols 64..127
    {
        f32x4 hacc[4][2];
        #pragma unroll
        for (int m = 0; m < 4; ++m) { hacc[m][0] = z; hacc[m][1] = z; }
        #pragma unroll
        for (int ks = 0; ks < 2; ++ks) {
            bf16x8 a[4];
            #pragma unroll
            for (int m = 0; m < 4; ++m)
                a[m] = *(const bf16x8*)(T_lds + aoff(wm * 64 + m * 16 + lr, ks * 4 + lg));
            #pragma unroll
            for (int n = 0; n < 2; ++n) {
                const int j = wn * 32 + n * 16 + lr;
                const bf16x8 bw = *(const bf16x8*)(fc11bf + (size_t)j * 64 + ks * 32 + lg * 8);
                #pragma unroll
                for (int m = 0; m < 4; ++m)
                    hacc[m][n] = __builtin_amdgcn_mfma_f32_16x16x32_bf16(a[m], bw, hacc[m][n], 0, 0, 0);
            }
        }
        #pragma unroll
        for (int n = 0; n < 2; ++n) {
            const int j = wn * 32 + n * 16 + lr;
            const float bj = fc11b[j];
            #pragma unroll
            for (int m = 0; m < 4; ++m)
                #pragma unroll
                for (int r = 0; r < 4; ++r) {
                    const int row = wm * 64 + m * 16 + lg * 4 + r;
                    *(__bf16*)(lds + eoff(row, 2 * (64 + j))) = bfc(hacc[m][n][r] + bj);
                }
        }
    }
    __syncthreads();

    // U = relu(E @ fc2W^T + fc2b) -> U_lds
    {
        f32x4 uacc[4][2];
        #pragma unroll
        for (int m = 0; m < 4; ++m) { uacc[m][0] = z; uacc[m][1] = z; }
        #pragma unroll
        for (int ks = 0; ks < 4; ++ks) {
            bf16x8 a[4];
            #pragma unroll
            for (int m = 0; m < 4; ++m) {
                const int row = wm * 64 + m * 16 + lr;
                a[m] = *(const bf16x8*)(lds + eoff(row, ks * 64 + lg * 16));
            }
            #pragma unroll
            for (int n = 0; n < 2; ++n) {
                const int j = wn * 32 + n * 16 + lr;
                const bf16x8 bw = *(const bf16x8*)(fc2bf + (size_t)j * 128 + ks * 32 + lg * 8);
                #pragma unroll
                for (int m = 0; m < 4; ++m)
                    uacc[m][n] = __builtin_amdgcn_mfma_f32_16x16x32_bf16(a[m], bw, uacc[m][n], 0, 0, 0);
            }
        }
        #pragma unroll
        for (int n = 0; n < 2; ++n) {
            const int j = wn * 32 + n * 16 + lr;
            const float bj = fc2b[j];
            #pragma unroll
            for (int m = 0; m < 4; ++m)
                #pragma unroll
                for (int r = 0; r < 4; ++r) {
                    const int row = wm * 64 + m * 16 + lg * 4 + r;
                    *(__bf16*)(U_lds + aoff(row, 0) - ((0 ^ ((row & 7) << 4))) // base row
                        + ((2 * j) ^ ((row & 7) << 4))) = bfc(fmaxf(uacc[m][n][r] + bj, 0.f));
                }
        }
    }
    __syncthreads();

    // out = (U @ fc21W^T + fc21b) * mask ; optionally emit mu^T bf16 tiles
    {
        f32x4 oacc[4][2];
        #pragma unroll
        for (int m = 0; m < 4; ++m) { oacc[m][0] = z; oacc[m][1] = z; }
        #pragma unroll
        for (int ks = 0; ks < 2; ++ks) {
            bf16x8 a[4];
            #pragma unroll
            for (int m = 0; m < 4; ++m)
                a[m] = *(const bf16x8*)(U_lds + aoff(wm * 64 + m * 16 + lr, ks * 4 + lg));
            #pragma unroll
            for (int n = 0; n < 2; ++n) {
                const int j = wn * 32 + n * 16 + lr;
                const bf16x8 bw = *(const bf16x8*)(fc21bf + (size_t)j * 64 + ks * 32 + lg * 8);
                #pragma unroll
                for (int m = 0; m < 4; ++m)
                    oacc[m][n] = __builtin_amdgcn_mfma_f32_16x16x32_bf16(a[m], bw, oacc[m][n], 0, 0, 0);
            }
        }
        #pragma unroll
        for (int n = 0; n < 2; ++n) {
            const int j = wn * 32 + n * 16 + lr;
            const float bj = fc21b[j];
            #pragma unroll
            for (int m = 0; m < 4; ++m)
                #pragma unroll
                for (int r = 0; r < 4; ++r) {
                    const int row = wm * 64 + m * 16 + lg * 4 + r;
                    const int g = b * DOUT + orow0 + row;
                    const float mval = mask[g];
                    const float o = (oacc[m][n][r] + bj) * mval;
                    out[(size_t)g * 64 + j] = o;
                    if (WRITE_T)   // stage bf16 transposed: [j][2*row ^ (j&7)<<4]
                        *(__bf16*)(lds + j * 256 + ((2 * row) ^ ((j & 7) << 4))) = bfc(o);
                }
        }
    }
    if (WRITE_T) {
        __syncthreads();
        // copy 2 tiles [p 64][swz 64k] linearly to ws (swizzles compose to identity)
        const int p = tid >> 2, cp = tid & 3;
        #pragma unroll
        for (int ti = 0; ti < 2; ++ti)
            #pragma unroll
            for (int q = 0; q < 2; ++q) {
                const int c = cp * 2 + q;
                const bf16x8 v = *(const bf16x8*)(lds + p * 256 + ti * 128 + c * 16);
                *(bf16x8*)(wsT + ((size_t)b * 64 + (orow0 >> 6) + ti) * 8192 + p * 128 + c * 16) = v;
            }
    }
}

extern "C" void kernel_launch(void* const* d_in, const int* in_sizes, int n_in,
                              void* d_out, int out_size, void* d_ws, size_t ws_size,
                              hipStream_t stream) {
    const float* mu0   = (const float*)d_in[0];
    const float* lb1   = (const float*)d_in[1];
    const float* ub1   = (const float*)d_in[2];
    const float* lb2   = (const float*)d_in[3];
    const float* ub2   = (const float*)d_in[4];
    const float* ps1   = (const float*)d_in[5];
    const float* ss1   = (const float*)d_in[6];
    const float* ps2   = (const float*)d_in[7];
    const float* ss2   = (const float*)d_in[8];
    const float* mask1 = (const float*)d_in[9];
    const float* mask2 = (const float*)d_in[10];
    const float* W1    = (const float*)d_in[11];
    const float* b1    = (const float*)d_in[12];
    const float* W2    = (const float*)d_in[13];
    const float* b2    = (const float*)d_in[14];
    const float* fc1W  = (const float*)d_in[15];
    const float* fc1b  = (const float*)d_in[16];
    const float* fc11W = (const float*)d_in[17];
    const float* fc11b = (const float*)d_in[18];
    const float* fc2W  = (const float*)d_in[19];
    const float* fc2b  = (const float*)d_in[20];
    const float* fc21W = (const float*)d_in[21];
    const float* fc21b = (const float*)d_in[22];

    char* ws = (char*)d_ws;
    float* mu1 = (float*)d_out;
    float* mu2 = (float*)d_out + (size_t)16 * 4096 * 64;
    const __bf16* fc11bf = (const __bf16*)(ws + WS_SM);
    const __bf16* fc2bf  = (const __bf16*)(ws + WS_SM) + 4096;
    const __bf16* fc21bf = (const __bf16*)(ws + WS_SM) + 12288;

    prepass_kernel<<<576, 256, 0, stream>>>(mu0, fc11W, fc2W, fc21W, ws);

    layer_kernel<2048, true><<<512, 256, 0, stream>>>(
        W1, b1, ws + WS_MU0, lb1, ub1, ps1, ss1, mask1,
        fc1W, fc1b, fc11bf, fc11b, fc2bf, fc2b, fc21bf, fc21b,
        mu1, ws + WS_MU1);

    layer_kernel<4096, false><<<512, 256, 0, stream>>>(
        W2, b2, ws + WS_MU1, lb2, ub2, ps2, ss2, mask2,
        fc1W, fc1b, fc11bf, fc11b, fc2bf, fc2b, fc21bf, fc21b,
        mu2, nullptr);
}

// Round 5
// 258.573 us; speedup vs baseline: 1.4970x; 1.4970x over previous
//
#include <hip/hip_runtime.h>
#include <hip/hip_bf16.h>

// EmbedLayerUpdate, round 5 (round-4 design, compile fix: no LDS pointer arrays).
// pre = W @ mu + b per batch ([4096,K]x[K,64]), fused relu-block epilogue.
// A: coalesced global fp32 -> reg -> cvt -> LDS [row][k] bf16 (XOR-swizzled),
//    T14 split (issue loads before MFMA, write LDS after).
// B: ws-pretransposed bf16 swizzled tiles, global_load_lds (linear).
// 2-barrier double-buffered loop, 48KB LDS, 3 blocks/CU, XCD-bijective grid.

#define DOUT 4096
typedef __bf16 bf16x8 __attribute__((ext_vector_type(8)));
typedef float  f32x4  __attribute__((ext_vector_type(4)));
typedef unsigned int u32;

__device__ __forceinline__ __bf16 bfc(float x) { return (__bf16)x; }

__device__ __forceinline__ bf16x8 cvt8(const float4 a, const float4 b) {
    bf16x8 r;
    r[0]=bfc(a.x); r[1]=bfc(a.y); r[2]=bfc(a.z); r[3]=bfc(a.w);
    r[4]=bfc(b.x); r[5]=bfc(b.y); r[6]=bfc(b.z); r[7]=bfc(b.w);
    return r;
}

__device__ __forceinline__ void gl_lds16(const void* g, void* l) {
    __builtin_amdgcn_global_load_lds(
        (const __attribute__((address_space(1))) u32*)g,
        (__attribute__((address_space(3))) u32*)l, 16, 0, 0);
}

// 128-byte rows (64 bf16): XOR-swizzle 16B chunks with row&7
__device__ __forceinline__ int aoff(int r, int c16) {
    return (r << 7) + ((c16 << 4) ^ ((r & 7) << 4));
}
// 256-byte rows (128 bf16): XOR-swizzle with row&15
__device__ __forceinline__ int eoff(int r, int byteoff) {
    return (r << 8) + (byteoff ^ ((r & 15) << 4));
}
// B-tile read: [p][swz k] rows of 128B
__device__ __forceinline__ int boff(int p, int kbyte) {
    return (p << 7) + (kbyte ^ ((p & 7) << 4));
}

#define WS_MU0 0
#define WS_MU1 (4u << 20)
#define WS_SM  (12u << 20)

// ---------------- prepass: mu0 -> bf16 transposed swizzled tiles; small weights -> bf16 ----------------
__global__ __launch_bounds__(256)
void prepass_kernel(const float* __restrict__ mu0, const float* __restrict__ fc11W,
                    const float* __restrict__ fc2W, const float* __restrict__ fc21W,
                    char* __restrict__ ws)
{
    const int blk = blockIdx.x, t = threadIdx.x;
    if (blk < 512) {                       // mu0t: [b 16][kt 32] tiles of [p 64][swz 64k]
        const int b = blk >> 5, kt = blk & 31;
        const int p = t & 63, kc = t >> 6; // kc in 0..3, 16 k each
        const float* src = mu0 + ((size_t)b * 2048 + kt * 64 + kc * 16) * 64 + p;
        char* tile = ws + WS_MU0 + ((size_t)b * 32 + kt) * 8192;
        float v[16];
        #pragma unroll
        for (int i = 0; i < 16; ++i) v[i] = src[(size_t)i * 64];
        bf16x8 o0, o1;
        #pragma unroll
        for (int i = 0; i < 8; ++i) { o0[i] = bfc(v[i]); o1[i] = bfc(v[8 + i]); }
        const int c0 = (kc * 2) ^ (p & 7), c1 = (kc * 2 + 1) ^ (p & 7);
        *(bf16x8*)(tile + p * 128 + c0 * 16) = o0;
        *(bf16x8*)(tile + p * 128 + c1 * 16) = o1;
    } else {                               // small weights: fc11 | fc2 | fc21 (bf16)
        const int idx = (blk - 512) * 256 + t;
        __bf16* dst = (__bf16*)(ws + WS_SM);
        if (idx < 4096)        dst[idx] = bfc(fc11W[idx]);
        else if (idx < 12288)  dst[idx] = bfc(fc2W[idx - 4096]);
        else                   dst[idx] = bfc(fc21W[idx - 12288]);
    }
}

// ---------------- layer kernel ----------------
template <int K, bool WRITE_T>
__global__ __launch_bounds__(256, 3)
void layer_kernel(const float* __restrict__ W, const float* __restrict__ bias,
                  const char* __restrict__ wsB,
                  const float* __restrict__ lb, const float* __restrict__ ub,
                  const float* __restrict__ ps, const float* __restrict__ ss,
                  const float* __restrict__ mask,
                  const float* __restrict__ fc1W, const float* __restrict__ fc1b,
                  const __bf16* __restrict__ fc11bf, const float* __restrict__ fc11b,
                  const __bf16* __restrict__ fc2bf, const float* __restrict__ fc2b,
                  const __bf16* __restrict__ fc21bf, const float* __restrict__ fc21b,
                  float* __restrict__ out, char* __restrict__ wsT)
{
    constexpr int NT = K / 64;
    __shared__ __align__(16) char lds[49152];
    // main loop: A bufs at 0/16K (16KB each), B bufs at 32K/40K (8KB each)
    // epilogue:  E at 0 (32KB), T at 32K (16KB), U reuses T slot.
    char* const T_lds = lds + 32768;

    const int tid = threadIdx.x;
    const int lane = tid & 63, wv = tid >> 6;
    const int wm = wv >> 1, wn = wv & 1;
    const int lr = lane & 15, lg = lane >> 4;

    // XCD-bijective swizzle: 512 = 8 xcd * 64; each XCD: 4 panels x 16 batches
    const int id = blockIdx.x;
    const int vid = (id & 7) * 64 + (id >> 3);
    const int panel = vid >> 4;
    const int b = vid & 15;
    const int orow0 = panel * 128;

    const char* bSrc = wsB + ((size_t)b * NT) * 8192;
    const int arow = tid >> 1, ahalf = tid & 1;
    const float* aSrc = W + (size_t)(orow0 + arow) * K + ahalf * 32;

    const f32x4 z = {0.f, 0.f, 0.f, 0.f};
    f32x4 acc[4][2];
    #pragma unroll
    for (int m = 0; m < 4; ++m) { acc[m][0] = z; acc[m][1] = z; }

    float4 ar[8];

    // prologue: stage tile 0 completely into buf 0
    gl_lds16(bSrc + (size_t)(wv * 128 + lane) * 16,      lds + 32768 + (wv * 128) * 16);
    gl_lds16(bSrc + (size_t)(wv * 128 + 64 + lane) * 16, lds + 32768 + (wv * 128 + 64) * 16);
    #pragma unroll
    for (int c = 0; c < 8; ++c) ar[c] = *(const float4*)(aSrc + c * 4);
    #pragma unroll
    for (int c = 0; c < 4; ++c)
        *(bf16x8*)(lds + aoff(arow, ahalf * 4 + c)) = cvt8(ar[2 * c], ar[2 * c + 1]);

    int cur = 0;
    for (int t = 0; t < NT; ++t) {
        __syncthreads();                       // stage(t) visible (drains vmcnt+lgkm)
        char* const curA = lds + (cur << 14);
        char* const nxtA = lds + ((cur ^ 1) << 14);
        char* const curB = lds + 32768 + (cur << 13);
        char* const nxtB = lds + 32768 + ((cur ^ 1) << 13);
        if (t + 1 < NT) {                      // T14: issue loads before compute
            const char* s = bSrc + (size_t)(t + 1) * 8192;
            gl_lds16(s + (size_t)(wv * 128 + lane) * 16,      nxtB + (wv * 128) * 16);
            gl_lds16(s + (size_t)(wv * 128 + 64 + lane) * 16, nxtB + (wv * 128 + 64) * 16);
            const float* as = aSrc + (size_t)(t + 1) * 64;
            #pragma unroll
            for (int c = 0; c < 8; ++c) ar[c] = *(const float4*)(as + c * 4);
        }
        #pragma unroll
        for (int ks = 0; ks < 2; ++ks) {       // compute tile t
            bf16x8 a[4], bb[2];
            #pragma unroll
            for (int m = 0; m < 4; ++m)
                a[m] = *(const bf16x8*)(curA + aoff(wm * 64 + m * 16 + lr, ks * 4 + lg));
            #pragma unroll
            for (int n = 0; n < 2; ++n)
                bb[n] = *(const bf16x8*)(curB + boff(wn * 32 + n * 16 + lr, ks * 64 + lg * 16));
            #pragma unroll
            for (int m = 0; m < 4; ++m)
                #pragma unroll
                for (int n = 0; n < 2; ++n)
                    acc[m][n] = __builtin_amdgcn_mfma_f32_16x16x32_bf16(a[m], bb[n], acc[m][n], 0, 0, 0);
        }
        if (t + 1 < NT) {                      // T14: write A(t+1) after compute
            #pragma unroll
            for (int c = 0; c < 4; ++c)
                *(bf16x8*)(nxtA + aoff(arow, ahalf * 4 + c)) = cvt8(ar[2 * c], ar[2 * c + 1]);
        }
        cur ^= 1;
    }
    __syncthreads();                           // main-loop LDS dead; reuse for epilogue

    // ---------------- epilogue ----------------
    // T = relu(info @ fc1W^T + fc1b) -> T_lds ; pre+bias -> E cols 0..63
    {
        const int row = tid >> 1;
        const int j0 = (tid & 1) * 32;
        const int g = b * DOUT + orow0 + row;
        const float lv = lb[g], uv = ub[g];
        const float lt = fminf(lv, 0.f), ut = fmaxf(uv, 0.f);
        const float diff = ut - lt;
        const float urr = ut / (diff + 1e-8f);
        const float lrr = 1.f - urr, i3 = ps[g], i4 = ss[g];
        #pragma unroll
        for (int c = 0; c < 4; ++c) {
            bf16x8 v;
            #pragma unroll
            for (int jj = 0; jj < 8; ++jj) {
                const int j = j0 + c * 8 + jj;
                const float* w = fc1W + j * 5;
                const float tv = fc1b[j] + urr * w[0] + lrr * w[1] + diff * w[2]
                               + i3 * w[3] + i4 * w[4];
                v[jj] = bfc(fmaxf(tv, 0.f));
            }
            *(bf16x8*)(T_lds + aoff(row, (j0 >> 3) + c)) = v;
        }
    }
    #pragma unroll
    for (int m = 0; m < 4; ++m)
        #pragma unroll
        for (int n = 0; n < 2; ++n) {
            const int col = wn * 32 + n * 16 + lr;
            #pragma unroll
            for (int r = 0; r < 4; ++r) {
                const int row = wm * 64 + m * 16 + lg * 4 + r;
                const float bs = bias[orow0 + row];
                *(__bf16*)(lds + eoff(row, 2 * col)) = bfc(acc[m][n][r] + bs);
            }
        }
    __syncthreads();

    // H = T @ fc11W^T + fc11b -> E cols 64..127
    {
        f32x4 hacc[4][2];
        #pragma unroll
        for (int m = 0; m < 4; ++m) { hacc[m][0] = z; hacc[m][1] = z; }
        #pragma unroll
        for (int ks = 0; ks < 2; ++ks) {
            bf16x8 a[4];
            #pragma unroll
            for (int m = 0; m < 4; ++m)
                a[m] = *(const bf16x8*)(T_lds + aoff(wm * 64 + m * 16 + lr, ks * 4 + lg));
            #pragma unroll
            for (int n = 0; n < 2; ++n) {
                const int j = wn * 32 + n * 16 + lr;
                const bf16x8 bw = *(const bf16x8*)(fc11bf + (size_t)j * 64 + ks * 32 + lg * 8);
                #pragma unroll
                for (int m = 0; m < 4; ++m)
                    hacc[m][n] = __builtin_amdgcn_mfma_f32_16x16x32_bf16(a[m], bw, hacc[m][n], 0, 0, 0);
            }
        }
        #pragma unroll
        for (int n = 0; n < 2; ++n) {
            const int j = wn * 32 + n * 16 + lr;
            const float bj = fc11b[j];
            #pragma unroll
            for (int m = 0; m < 4; ++m)
                #pragma unroll
                for (int r = 0; r < 4; ++r) {
                    const int row = wm * 64 + m * 16 + lg * 4 + r;
                    *(__bf16*)(lds + eoff(row, 2 * (64 + j))) = bfc(hacc[m][n][r] + bj);
                }
        }
    }
    __syncthreads();

    // U = relu(E @ fc2W^T + fc2b) -> T_lds slot (T dead after reads)
    {
        f32x4 uacc[4][2];
        #pragma unroll
        for (int m = 0; m < 4; ++m) { uacc[m][0] = z; uacc[m][1] = z; }
        #pragma unroll
        for (int ks = 0; ks < 4; ++ks) {
            bf16x8 a[4];
            #pragma unroll
            for (int m = 0; m < 4; ++m) {
                const int row = wm * 64 + m * 16 + lr;
                a[m] = *(const bf16x8*)(lds + eoff(row, ks * 64 + lg * 16));
            }
            #pragma unroll
            for (int n = 0; n < 2; ++n) {
                const int j = wn * 32 + n * 16 + lr;
                const bf16x8 bw = *(const bf16x8*)(fc2bf + (size_t)j * 128 + ks * 32 + lg * 8);
                #pragma unroll
                for (int m = 0; m < 4; ++m)
                    uacc[m][n] = __builtin_amdgcn_mfma_f32_16x16x32_bf16(a[m], bw, uacc[m][n], 0, 0, 0);
            }
        }
        __syncthreads();   // T reads (H stage) and E reads done before overwriting T slot
        #pragma unroll
        for (int n = 0; n < 2; ++n) {
            const int j = wn * 32 + n * 16 + lr;
            const float bj = fc2b[j];
            #pragma unroll
            for (int m = 0; m < 4; ++m)
                #pragma unroll
                for (int r = 0; r < 4; ++r) {
                    const int row = wm * 64 + m * 16 + lg * 4 + r;
                    *(__bf16*)(T_lds + (row << 7) + ((2 * j) ^ ((row & 7) << 4))) =
                        bfc(fmaxf(uacc[m][n][r] + bj, 0.f));
                }
        }
    }
    __syncthreads();

    // out = (U @ fc21W^T + fc21b) * mask ; optionally emit mu^T bf16 tiles
    {
        f32x4 oacc[4][2];
        #pragma unroll
        for (int m = 0; m < 4; ++m) { oacc[m][0] = z; oacc[m][1] = z; }
        #pragma unroll
        for (int ks = 0; ks < 2; ++ks) {
            bf16x8 a[4];
            #pragma unroll
            for (int m = 0; m < 4; ++m)
                a[m] = *(const bf16x8*)(T_lds + aoff(wm * 64 + m * 16 + lr, ks * 4 + lg));
            #pragma unroll
            for (int n = 0; n < 2; ++n) {
                const int j = wn * 32 + n * 16 + lr;
                const bf16x8 bw = *(const bf16x8*)(fc21bf + (size_t)j * 64 + ks * 32 + lg * 8);
                #pragma unroll
                for (int m = 0; m < 4; ++m)
                    oacc[m][n] = __builtin_amdgcn_mfma_f32_16x16x32_bf16(a[m], bw, oacc[m][n], 0, 0, 0);
            }
        }
        #pragma unroll
        for (int n = 0; n < 2; ++n) {
            const int j = wn * 32 + n * 16 + lr;
            const float bj = fc21b[j];
            #pragma unroll
            for (int m = 0; m < 4; ++m)
                #pragma unroll
                for (int r = 0; r < 4; ++r) {
                    const int row = wm * 64 + m * 16 + lg * 4 + r;
                    const int g = b * DOUT + orow0 + row;
                    const float mval = mask[g];
                    const float o = (oacc[m][n][r] + bj) * mval;
                    out[(size_t)g * 64 + j] = o;
                    if (WRITE_T)   // stage bf16 transposed in E region (dead)
                        *(__bf16*)(lds + j * 256 + ((2 * row) ^ ((j & 7) << 4))) = bfc(o);
                }
        }
    }
    if (WRITE_T) {
        __syncthreads();
        const int p = tid >> 2, cp = tid & 3;
        #pragma unroll
        for (int ti = 0; ti < 2; ++ti)
            #pragma unroll
            for (int q = 0; q < 2; ++q) {
                const int c = cp * 2 + q;
                const bf16x8 v = *(const bf16x8*)(lds + p * 256 + ti * 128 + c * 16);
                *(bf16x8*)(wsT + ((size_t)b * 64 + (orow0 >> 6) + ti) * 8192 + p * 128 + c * 16) = v;
            }
    }
}

extern "C" void kernel_launch(void* const* d_in, const int* in_sizes, int n_in,
                              void* d_out, int out_size, void* d_ws, size_t ws_size,
                              hipStream_t stream) {
    const float* mu0   = (const float*)d_in[0];
    const float* lb1   = (const float*)d_in[1];
    const float* ub1   = (const float*)d_in[2];
    const float* lb2   = (const float*)d_in[3];
    const float* ub2   = (const float*)d_in[4];
    const float* ps1   = (const float*)d_in[5];
    const float* ss1   = (const float*)d_in[6];
    const float* ps2   = (const float*)d_in[7];
    const float* ss2   = (const float*)d_in[8];
    const float* mask1 = (const float*)d_in[9];
    const float* mask2 = (const float*)d_in[10];
    const float* W1    = (const float*)d_in[11];
    const float* b1    = (const float*)d_in[12];
    const float* W2    = (const float*)d_in[13];
    const float* b2    = (const float*)d_in[14];
    const float* fc1W  = (const float*)d_in[15];
    const float* fc1b  = (const float*)d_in[16];
    const float* fc11W = (const float*)d_in[17];
    const float* fc11b = (const float*)d_in[18];
    const float* fc2W  = (const float*)d_in[19];
    const float* fc2b  = (const float*)d_in[20];
    const float* fc21W = (const float*)d_in[21];
    const float* fc21b = (const float*)d_in[22];

    char* ws = (char*)d_ws;
    float* mu1 = (float*)d_out;
    float* mu2 = (float*)d_out + (size_t)16 * 4096 * 64;
    const __bf16* fc11bf = (const __bf16*)(ws + WS_SM);
    const __bf16* fc2bf  = (const __bf16*)(ws + WS_SM) + 4096;
    const __bf16* fc21bf = (const __bf16*)(ws + WS_SM) + 12288;

    prepass_kernel<<<576, 256, 0, stream>>>(mu0, fc11W, fc2W, fc21W, ws);

    layer_kernel<2048, true><<<512, 256, 0, stream>>>(
        W1, b1, ws + WS_MU0, lb1, ub1, ps1, ss1, mask1,
        fc1W, fc1b, fc11bf, fc11b, fc2bf, fc2b, fc21bf, fc21b,
        mu1, ws + WS_MU1);

    layer_kernel<4096, false><<<512, 256, 0, stream>>>(
        W2, b2, ws + WS_MU1, lb2, ub2, ps2, ss2, mask2,
        fc1W, fc1b, fc11bf, fc11b, fc2bf, fc2b, fc21bf, fc21b,
        mu2, nullptr);
}

// Round 6
// 131.923 us; speedup vs baseline: 2.9342x; 1.9600x over previous
//
#include <hip/hip_runtime.h>
#include <hip/hip_bf16.h>

// EmbedLayerUpdate, round 6.
// pre = W @ mu + b per batch ([4096,K]x[K,64]), fused relu-block epilogue.
// Main loop: raw s_barrier + counted vmcnt (loads stay in flight across the
// barrier). A: coalesced fp32 (16 lanes/row) -> reg -> cvt -> swizzled LDS,
// 2-deep. B: ws-pretransposed bf16 tiles via global_load_lds, 3-deep.
// 56KB LDS, 2 blocks/CU, XCD-bijective grid. B=16, P=64.

#define DOUT 4096
typedef __bf16 bf16x8 __attribute__((ext_vector_type(8)));
typedef float  f32x4  __attribute__((ext_vector_type(4)));
typedef unsigned int u32;

__device__ __forceinline__ __bf16 bfc(float x) { return (__bf16)x; }

__device__ __forceinline__ bf16x8 cvt8(const float4 a, const float4 b) {
    bf16x8 r;
    r[0]=bfc(a.x); r[1]=bfc(a.y); r[2]=bfc(a.z); r[3]=bfc(a.w);
    r[4]=bfc(b.x); r[5]=bfc(b.y); r[6]=bfc(b.z); r[7]=bfc(b.w);
    return r;
}

__device__ __forceinline__ void gl_lds16(const void* g, void* l) {
    __builtin_amdgcn_global_load_lds(
        (const __attribute__((address_space(1))) u32*)g,
        (__attribute__((address_space(3))) u32*)l, 16, 0, 0);
}

// 128-byte rows (64 bf16): XOR-swizzle 16B chunks with row&7
__device__ __forceinline__ int aoff(int r, int c16) {
    return (r << 7) + ((c16 << 4) ^ ((r & 7) << 4));
}
// 256-byte rows (128 bf16): XOR-swizzle with row&15
__device__ __forceinline__ int eoff(int r, int byteoff) {
    return (r << 8) + (byteoff ^ ((r & 15) << 4));
}
// B-tile read: [p][swz k] rows of 128B
__device__ __forceinline__ int boff(int p, int kbyte) {
    return (p << 7) + (kbyte ^ ((p & 7) << 4));
}

#define WS_MU0 0
#define WS_MU1 (4u << 20)
#define WS_SM  (12u << 20)

#define BAR() asm volatile("s_barrier" ::: "memory")

// ---------------- prepass: mu0 -> bf16 transposed swizzled tiles; small weights -> bf16 ----------------
__global__ __launch_bounds__(256)
void prepass_kernel(const float* __restrict__ mu0, const float* __restrict__ fc11W,
                    const float* __restrict__ fc2W, const float* __restrict__ fc21W,
                    char* __restrict__ ws)
{
    const int blk = blockIdx.x, t = threadIdx.x;
    if (blk < 512) {                       // mu0t: [b 16][kt 32] tiles of [p 64][swz 64k]
        const int b = blk >> 5, kt = blk & 31;
        const int p = t & 63, kc = t >> 6; // kc in 0..3, 16 k each
        const float* src = mu0 + ((size_t)b * 2048 + kt * 64 + kc * 16) * 64 + p;
        char* tile = ws + WS_MU0 + ((size_t)b * 32 + kt) * 8192;
        float v[16];
        #pragma unroll
        for (int i = 0; i < 16; ++i) v[i] = src[(size_t)i * 64];
        bf16x8 o0, o1;
        #pragma unroll
        for (int i = 0; i < 8; ++i) { o0[i] = bfc(v[i]); o1[i] = bfc(v[8 + i]); }
        const int c0 = (kc * 2) ^ (p & 7), c1 = (kc * 2 + 1) ^ (p & 7);
        *(bf16x8*)(tile + p * 128 + c0 * 16) = o0;
        *(bf16x8*)(tile + p * 128 + c1 * 16) = o1;
    } else {                               // small weights: fc11 | fc2 | fc21 (bf16)
        const int idx = (blk - 512) * 256 + t;
        __bf16* dst = (__bf16*)(ws + WS_SM);
        if (idx < 4096)        dst[idx] = bfc(fc11W[idx]);
        else if (idx < 12288)  dst[idx] = bfc(fc2W[idx - 4096]);
        else                   dst[idx] = bfc(fc21W[idx - 12288]);
    }
}

// ---------------- layer kernel ----------------
template <int K, bool WRITE_T>
__global__ __launch_bounds__(256, 2)
void layer_kernel(const float* __restrict__ W, const float* __restrict__ bias,
                  const char* __restrict__ wsB,
                  const float* __restrict__ lb, const float* __restrict__ ub,
                  const float* __restrict__ ps, const float* __restrict__ ss,
                  const float* __restrict__ mask,
                  const float* __restrict__ fc1W, const float* __restrict__ fc1b,
                  const __bf16* __restrict__ fc11bf, const float* __restrict__ fc11b,
                  const __bf16* __restrict__ fc2bf, const float* __restrict__ fc2b,
                  const __bf16* __restrict__ fc21bf, const float* __restrict__ fc21b,
                  float* __restrict__ out, char* __restrict__ wsT)
{
    constexpr int NT = K / 64;
    __shared__ __align__(16) char lds[57344];
    // main loop: A bufs at 0/16K (16KB each), B bufs at 32K/40K/48K (8KB each)
    // epilogue:  E at 0 (32KB), T at 32K (16KB), U reuses T slot.
    char* const T_lds = lds + 32768;

    const int tid = threadIdx.x;
    const int lane = tid & 63, wv = tid >> 6;
    const int wm = wv >> 1, wn = wv & 1;
    const int lr = lane & 15, lg = lane >> 4;

    // XCD-bijective swizzle: 512 = 8 xcd * 64; each XCD: 4 panels x 16 batches
    const int id = blockIdx.x;
    const int vid = (id & 7) * 64 + (id >> 3);
    const int panel = vid >> 4;
    const int b = vid & 15;
    const int orow0 = panel * 128;

    const char* bSrc = wsB + ((size_t)b * NT) * 8192;

    // A loader: row = 32p + (tid>>3), slot = tid&7 (16B k-chunk). 16 lanes/row
    // -> 256B contiguous per row per instruction (coalesced).
    const int row0 = tid >> 3, slot = tid & 7;
    const float* aBase = W + (size_t)(orow0 + row0) * K + slot * 8;
    const int awoff = row0 * 128 + ((slot ^ (row0 & 7)) << 4);  // +p*4096 per pass

    const f32x4 z = {0.f, 0.f, 0.f, 0.f};
    f32x4 acc[4][2];
    #pragma unroll
    for (int m = 0; m < 4; ++m) { acc[m][0] = z; acc[m][1] = z; }

    float4 ar[4][2];

    // ---------- prologue: issue A(0), B(0), B(1); land A(0)+B(0) ----------
    #pragma unroll
    for (int p = 0; p < 4; ++p) {
        const float* s = aBase + (size_t)(32 * p) * K;
        ar[p][0] = *(const float4*)s;
        ar[p][1] = *(const float4*)(s + 4);
    }
    gl_lds16(bSrc + (size_t)(wv * 128 + lane) * 16,             lds + 32768 + (wv * 128) * 16);
    gl_lds16(bSrc + (size_t)(wv * 128 + 64 + lane) * 16,        lds + 32768 + (wv * 128 + 64) * 16);
    gl_lds16(bSrc + 8192 + (size_t)(wv * 128 + lane) * 16,      lds + 40960 + (wv * 128) * 16);
    gl_lds16(bSrc + 8192 + (size_t)(wv * 128 + 64 + lane) * 16, lds + 40960 + (wv * 128 + 64) * 16);
    asm volatile("s_waitcnt vmcnt(2)" ::: "memory");   // A(0)+B(0) done, B(1) in flight
    #pragma unroll
    for (int p = 0; p < 4; ++p)
        *(bf16x8*)(lds + awoff + p * 4096) = cvt8(ar[p][0], ar[p][1]);
    asm volatile("s_waitcnt lgkmcnt(0)" ::: "memory");

    // ---------- main loop: 1 barrier/iter, counted vmcnt ----------
    for (int t = 0; t < NT; ++t) {
        BAR();
        if (t + 1 < NT) {                  // issue A(t+1) -> regs
            const float* s0 = aBase + (size_t)(t + 1) * 64;
            #pragma unroll
            for (int p = 0; p < 4; ++p) {
                const float* s = s0 + (size_t)(32 * p) * K;
                ar[p][0] = *(const float4*)s;
                ar[p][1] = *(const float4*)(s + 4);
            }
        }
        if (t + 2 < NT) {                  // issue B(t+2) -> LDS (3-deep)
            const char* s = bSrc + (size_t)(t + 2) * 8192;
            char* d = lds + 32768 + ((t + 2) % 3) * 8192;
            gl_lds16(s + (size_t)(wv * 128 + lane) * 16,      d + (wv * 128) * 16);
            gl_lds16(s + (size_t)(wv * 128 + 64 + lane) * 16, d + (wv * 128 + 64) * 16);
        }
        {                                  // compute tile t
            const char* cA = lds + ((t & 1) << 14);
            const char* cB = lds + 32768 + (t % 3) * 8192;
            __builtin_amdgcn_s_setprio(1);
            #pragma unroll
            for (int ks = 0; ks < 2; ++ks) {
                bf16x8 a[4], bb[2];
                #pragma unroll
                for (int m = 0; m < 4; ++m)
                    a[m] = *(const bf16x8*)(cA + aoff(wm * 64 + m * 16 + lr, ks * 4 + lg));
                #pragma unroll
                for (int n = 0; n < 2; ++n)
                    bb[n] = *(const bf16x8*)(cB + boff(wn * 32 + n * 16 + lr, ks * 64 + lg * 16));
                #pragma unroll
                for (int m = 0; m < 4; ++m)
                    #pragma unroll
                    for (int n = 0; n < 2; ++n)
                        acc[m][n] = __builtin_amdgcn_mfma_f32_16x16x32_bf16(a[m], bb[n], acc[m][n], 0, 0, 0);
            }
            __builtin_amdgcn_s_setprio(0);
        }
        // wait A(t+1)+B(t+1) landed; keep B(t+2) in flight
        if (t + 2 < NT) asm volatile("s_waitcnt vmcnt(2)" ::: "memory");
        else            asm volatile("s_waitcnt vmcnt(0)" ::: "memory");
        if (t + 1 < NT) {                  // write A(t+1) to other buf
            char* dA = lds + (((t + 1) & 1) << 14);
            #pragma unroll
            for (int p = 0; p < 4; ++p)
                *(bf16x8*)(dA + awoff + p * 4096) = cvt8(ar[p][0], ar[p][1]);
        }
        asm volatile("s_waitcnt lgkmcnt(0)" ::: "memory");
    }
    __syncthreads();                       // main-loop LDS dead; reuse for epilogue

    // ---------------- epilogue ----------------
    // T = relu(info @ fc1W^T + fc1b) -> T_lds ; pre+bias -> E cols 0..63
    {
        const int row = tid >> 1;
        const int j0 = (tid & 1) * 32;
        const int g = b * DOUT + orow0 + row;
        const float lv = lb[g], uv = ub[g];
        const float lt = fminf(lv, 0.f), ut = fmaxf(uv, 0.f);
        const float diff = ut - lt;
        const float urr = ut / (diff + 1e-8f);
        const float lrr = 1.f - urr, i3 = ps[g], i4 = ss[g];
        #pragma unroll
        for (int c = 0; c < 4; ++c) {
            bf16x8 v;
            #pragma unroll
            for (int jj = 0; jj < 8; ++jj) {
                const int j = j0 + c * 8 + jj;
                const float* w = fc1W + j * 5;
                const float tv = fc1b[j] + urr * w[0] + lrr * w[1] + diff * w[2]
                               + i3 * w[3] + i4 * w[4];
                v[jj] = bfc(fmaxf(tv, 0.f));
            }
            *(bf16x8*)(T_lds + aoff(row, (j0 >> 3) + c)) = v;
        }
    }
    #pragma unroll
    for (int m = 0; m < 4; ++m)
        #pragma unroll
        for (int n = 0; n < 2; ++n) {
            const int col = wn * 32 + n * 16 + lr;
            #pragma unroll
            for (int r = 0; r < 4; ++r) {
                const int row = wm * 64 + m * 16 + lg * 4 + r;
                const float bs = bias[orow0 + row];
                *(__bf16*)(lds + eoff(row, 2 * col)) = bfc(acc[m][n][r] + bs);
            }
        }
    __syncthreads();

    // H = T @ fc11W^T + fc11b -> E cols 64..127
    {
        f32x4 hacc[4][2];
        #pragma unroll
        for (int m = 0; m < 4; ++m) { hacc[m][0] = z; hacc[m][1] = z; }
        #pragma unroll
        for (int ks = 0; ks < 2; ++ks) {
            bf16x8 a[4];
            #pragma unroll
            for (int m = 0; m < 4; ++m)
                a[m] = *(const bf16x8*)(T_lds + aoff(wm * 64 + m * 16 + lr, ks * 4 + lg));
            #pragma unroll
            for (int n = 0; n < 2; ++n) {
                const int j = wn * 32 + n * 16 + lr;
                const bf16x8 bw = *(const bf16x8*)(fc11bf + (size_t)j * 64 + ks * 32 + lg * 8);
                #pragma unroll
                for (int m = 0; m < 4; ++m)
                    hacc[m][n] = __builtin_amdgcn_mfma_f32_16x16x32_bf16(a[m], bw, hacc[m][n], 0, 0, 0);
            }
        }
        #pragma unroll
        for (int n = 0; n < 2; ++n) {
            const int j = wn * 32 + n * 16 + lr;
            const float bj = fc11b[j];
            #pragma unroll
            for (int m = 0; m < 4; ++m)
                #pragma unroll
                for (int r = 0; r < 4; ++r) {
                    const int row = wm * 64 + m * 16 + lg * 4 + r;
                    *(__bf16*)(lds + eoff(row, 2 * (64 + j))) = bfc(hacc[m][n][r] + bj);
                }
        }
    }
    __syncthreads();

    // U = relu(E @ fc2W^T + fc2b) -> T_lds slot (T dead after reads)
    {
        f32x4 uacc[4][2];
        #pragma unroll
        for (int m = 0; m < 4; ++m) { uacc[m][0] = z; uacc[m][1] = z; }
        #pragma unroll
        for (int ks = 0; ks < 4; ++ks) {
            bf16x8 a[4];
            #pragma unroll
            for (int m = 0; m < 4; ++m) {
                const int row = wm * 64 + m * 16 + lr;
                a[m] = *(const bf16x8*)(lds + eoff(row, ks * 64 + lg * 16));
            }
            #pragma unroll
            for (int n = 0; n < 2; ++n) {
                const int j = wn * 32 + n * 16 + lr;
                const bf16x8 bw = *(const bf16x8*)(fc2bf + (size_t)j * 128 + ks * 32 + lg * 8);
                #pragma unroll
                for (int m = 0; m < 4; ++m)
                    uacc[m][n] = __builtin_amdgcn_mfma_f32_16x16x32_bf16(a[m], bw, uacc[m][n], 0, 0, 0);
            }
        }
        __syncthreads();   // T reads (H stage) and E reads done before overwriting T slot
        #pragma unroll
        for (int n = 0; n < 2; ++n) {
            const int j = wn * 32 + n * 16 + lr;
            const float bj = fc2b[j];
            #pragma unroll
            for (int m = 0; m < 4; ++m)
                #pragma unroll
                for (int r = 0; r < 4; ++r) {
                    const int row = wm * 64 + m * 16 + lg * 4 + r;
                    *(__bf16*)(T_lds + (row << 7) + ((2 * j) ^ ((row & 7) << 4))) =
                        bfc(fmaxf(uacc[m][n][r] + bj, 0.f));
                }
        }
    }
    __syncthreads();

    // out = (U @ fc21W^T + fc21b) * mask ; optionally emit mu^T bf16 tiles
    {
        f32x4 oacc[4][2];
        #pragma unroll
        for (int m = 0; m < 4; ++m) { oacc[m][0] = z; oacc[m][1] = z; }
        #pragma unroll
        for (int ks = 0; ks < 2; ++ks) {
            bf16x8 a[4];
            #pragma unroll
            for (int m = 0; m < 4; ++m)
                a[m] = *(const bf16x8*)(T_lds + aoff(wm * 64 + m * 16 + lr, ks * 4 + lg));
            #pragma unroll
            for (int n = 0; n < 2; ++n) {
                const int j = wn * 32 + n * 16 + lr;
                const bf16x8 bw = *(const bf16x8*)(fc21bf + (size_t)j * 64 + ks * 32 + lg * 8);
                #pragma unroll
                for (int m = 0; m < 4; ++m)
                    oacc[m][n] = __builtin_amdgcn_mfma_f32_16x16x32_bf16(a[m], bw, oacc[m][n], 0, 0, 0);
            }
        }
        #pragma unroll
        for (int n = 0; n < 2; ++n) {
            const int j = wn * 32 + n * 16 + lr;
            const float bj = fc21b[j];
            #pragma unroll
            for (int m = 0; m < 4; ++m)
                #pragma unroll
                for (int r = 0; r < 4; ++r) {
                    const int row = wm * 64 + m * 16 + lg * 4 + r;
                    const int g = b * DOUT + orow0 + row;
                    const float mval = mask[g];
                    const float o = (oacc[m][n][r] + bj) * mval;
                    out[(size_t)g * 64 + j] = o;
                    if (WRITE_T)   // stage bf16 transposed in E region (dead)
                        *(__bf16*)(lds + j * 256 + ((2 * row) ^ ((j & 7) << 4))) = bfc(o);
                }
        }
    }
    if (WRITE_T) {
        __syncthreads();
        const int p = tid >> 2, cp = tid & 3;
        #pragma unroll
        for (int ti = 0; ti < 2; ++ti)
            #pragma unroll
            for (int q = 0; q < 2; ++q) {
                const int c = cp * 2 + q;
                const bf16x8 v = *(const bf16x8*)(lds + p * 256 + ti * 128 + c * 16);
                *(bf16x8*)(wsT + ((size_t)b * 64 + (orow0 >> 6) + ti) * 8192 + p * 128 + c * 16) = v;
            }
    }
}

extern "C" void kernel_launch(void* const* d_in, const int* in_sizes, int n_in,
                              void* d_out, int out_size, void* d_ws, size_t ws_size,
                              hipStream_t stream) {
    const float* mu0   = (const float*)d_in[0];
    const float* lb1   = (const float*)d_in[1];
    const float* ub1   = (const float*)d_in[2];
    const float* lb2   = (const float*)d_in[3];
    const float* ub2   = (const float*)d_in[4];
    const float* ps1   = (const float*)d_in[5];
    const float* ss1   = (const float*)d_in[6];
    const float* ps2   = (const float*)d_in[7];
    const float* ss2   = (const float*)d_in[8];
    const float* mask1 = (const float*)d_in[9];
    const float* mask2 = (const float*)d_in[10];
    const float* W1    = (const float*)d_in[11];
    const float* b1    = (const float*)d_in[12];
    const float* W2    = (const float*)d_in[13];
    const float* b2    = (const float*)d_in[14];
    const float* fc1W  = (const float*)d_in[15];
    const float* fc1b  = (const float*)d_in[16];
    const float* fc11W = (const float*)d_in[17];
    const float* fc11b = (const float*)d_in[18];
    const float* fc2W  = (const float*)d_in[19];
    const float* fc2b  = (const float*)d_in[20];
    const float* fc21W = (const float*)d_in[21];
    const float* fc21b = (const float*)d_in[22];

    char* ws = (char*)d_ws;
    float* mu1 = (float*)d_out;
    float* mu2 = (float*)d_out + (size_t)16 * 4096 * 64;
    const __bf16* fc11bf = (const __bf16*)(ws + WS_SM);
    const __bf16* fc2bf  = (const __bf16*)(ws + WS_SM) + 4096;
    const __bf16* fc21bf = (const __bf16*)(ws + WS_SM) + 12288;

    prepass_kernel<<<576, 256, 0, stream>>>(mu0, fc11W, fc2W, fc21W, ws);

    layer_kernel<2048, true><<<512, 256, 0, stream>>>(
        W1, b1, ws + WS_MU0, lb1, ub1, ps1, ss1, mask1,
        fc1W, fc1b, fc11bf, fc11b, fc2bf, fc2b, fc21bf, fc21b,
        mu1, ws + WS_MU1);

    layer_kernel<4096, false><<<512, 256, 0, stream>>>(
        W2, b2, ws + WS_MU1, lb2, ub2, ps2, ss2, mask2,
        fc1W, fc1b, fc11bf, fc11b, fc2bf, fc2b, fc21bf, fc21b,
        mu2, nullptr);
}

// Round 7
// 126.024 us; speedup vs baseline: 3.0716x; 1.0468x over previous
//
#include <hip/hip_runtime.h>
#include <hip/hip_bf16.h>

// EmbedLayerUpdate, round 7.
// BM=64 x BN=256 (4 batches) blocks, grid 256 (1/CU), 4 waves, wave=64x64
// (one batch per wave). B = frag-ordered bf16 chunks in ws, loaded direct
// global->VGPR (no LDS). A = fp32 -> reg -> cvt -> swizzled LDS, dbuf.
// 2-deep prefetch, 1 s_barrier/iter, counted vmcnt. Fused relu-block epilogue
// in 2 passes of 128 rows. B=16, P=64, DOUT=4096.

#define DOUT 4096
typedef __bf16 bf16x8 __attribute__((ext_vector_type(8)));
typedef float  f32x4  __attribute__((ext_vector_type(4)));

__device__ __forceinline__ __bf16 bfc(float x) { return (__bf16)x; }

__device__ __forceinline__ bf16x8 cvt8(const float4 a, const float4 b) {
    bf16x8 r;
    r[0]=bfc(a.x); r[1]=bfc(a.y); r[2]=bfc(a.z); r[3]=bfc(a.w);
    r[4]=bfc(b.x); r[5]=bfc(b.y); r[6]=bfc(b.z); r[7]=bfc(b.w);
    return r;
}

// 128-byte rows (64 bf16): XOR-swizzle 16B chunks with row&7
__device__ __forceinline__ int aoff(int r, int c16) {
    return (r << 7) + ((c16 << 4) ^ ((r & 7) << 4));
}

#define WS_MU0 0
#define WS_MU1 (4u << 20)
#define WS_SM  (12u << 20)

#define BAR() asm volatile("s_barrier" ::: "memory")

// ---- prepass: mu0 -> frag-ordered bf16 tiles; small weights -> bf16 ----
// Tile (8KB) layout per (batch, kt): chunk(ks,n,lane) 16B holds
// mu[b][kt*64 + ks*32 + (lane>>4)*8 + e][n*16 + (lane&15)], e=0..7.
__global__ __launch_bounds__(256)
void prepass_kernel(const float* __restrict__ mu0, const float* __restrict__ fc11W,
                    const float* __restrict__ fc2W, const float* __restrict__ fc21W,
                    char* __restrict__ ws)
{
    const int blk = blockIdx.x, t = threadIdx.x;
    if (blk < 512) {
        const int b = blk >> 5, kt = blk & 31;
        const int p = t & 63, kc = t >> 6;       // kc 0..3: 16 k each
        const float* src = mu0 + ((size_t)b * 2048 + kt * 64 + kc * 16) * 64 + p;
        char* tile = ws + WS_MU0 + ((size_t)b * 32 + kt) * 8192;
        float v[16];
        #pragma unroll
        for (int i = 0; i < 16; ++i) v[i] = src[(size_t)i * 64];
        bf16x8 o0, o1;
        #pragma unroll
        for (int i = 0; i < 8; ++i) { o0[i] = bfc(v[i]); o1[i] = bfc(v[8 + i]); }
        const int n = p >> 4, ks = kc >> 1;
        const int l0 = (((kc & 1) * 2) << 4) | (p & 15);
        const int l1 = (((kc & 1) * 2 + 1) << 4) | (p & 15);
        *(bf16x8*)(tile + ks * 4096 + n * 1024 + l0 * 16) = o0;
        *(bf16x8*)(tile + ks * 4096 + n * 1024 + l1 * 16) = o1;
    } else {
        const int idx = (blk - 512) * 256 + t;
        __bf16* dst = (__bf16*)(ws + WS_SM);
        if (idx < 4096)        dst[idx] = bfc(fc11W[idx]);
        else if (idx < 12288)  dst[idx] = bfc(fc2W[idx - 4096]);
        else                   dst[idx] = bfc(fc21W[idx - 12288]);
    }
}

#define LOADA(dst, t_) { const float* s_ = aSrc + (size_t)(t_) * 64;            \
    dst[0] = *(const float4*)s_;       dst[1] = *(const float4*)(s_ + 4);       \
    dst[2] = *(const float4*)(s_ + 8); dst[3] = *(const float4*)(s_ + 12); }

#define LOADB(dst, t_) { const char* bp_ = bW + (size_t)(t_) * 8192 + lane * 16; \
    _Pragma("unroll")                                                            \
    for (int c_ = 0; c_ < 8; ++c_)                                               \
        dst[c_] = *(const bf16x8*)(bp_ + (c_ >> 2) * 4096 + (c_ & 3) * 1024); }

#define MFMAS(Abuf, bset) {                                                      \
    _Pragma("unroll")                                                            \
    for (int ks_ = 0; ks_ < 2; ++ks_) {                                          \
        bf16x8 af_[4];                                                           \
        _Pragma("unroll")                                                        \
        for (int m_ = 0; m_ < 4; ++m_)                                           \
            af_[m_] = *(const bf16x8*)((Abuf) + aoff(m_ * 16 + lr, ks_ * 4 + lg)); \
        _Pragma("unroll")                                                        \
        for (int m_ = 0; m_ < 4; ++m_)                                           \
            _Pragma("unroll")                                                    \
            for (int n_ = 0; n_ < 4; ++n_)                                       \
                acc[m_][n_] = __builtin_amdgcn_mfma_f32_16x16x32_bf16(           \
                    af_[m_], bset[ks_ * 4 + n_], acc[m_][n_], 0, 0, 0);          \
    } }

// ---------------- layer kernel ----------------
template <int K, bool WRITE_T>
__global__ __launch_bounds__(256, 1)
void layer_kernel(const float* __restrict__ W, const float* __restrict__ bias,
                  const char* __restrict__ wsB,
                  const float* __restrict__ lb, const float* __restrict__ ub,
                  const float* __restrict__ ps, const float* __restrict__ ss,
                  const float* __restrict__ mask,
                  const float* __restrict__ fc1W, const float* __restrict__ fc1b,
                  const __bf16* __restrict__ fc11bf, const float* __restrict__ fc11b,
                  const __bf16* __restrict__ fc2bf, const float* __restrict__ fc2b,
                  const __bf16* __restrict__ fc21bf, const float* __restrict__ fc21b,
                  float* __restrict__ out, char* __restrict__ wsT)
{
    constexpr int NT = K / 64;
    __shared__ __align__(16) char lds[65536];
    // main: Abuf0 @0 (8KB), Abuf1 @8K.  epilogue: T/U @0 (16KB),
    // hold(batches 2,3 pre) @16K (16KB), preE/WT @32K (16KB), H @48K (16KB).
    char* const T_lds = lds;
    char* const hold  = lds + 16384;
    char* const preE  = lds + 32768;
    char* const H_lds = lds + 49152;

    const int tid = threadIdx.x;
    const int lane = tid & 63, wv = tid >> 6;
    const int lr = lane & 15, lg = lane >> 4;

    // 256 blocks = 8 XCD x 32: each XCD gets 8 panels x 4 bgroups
    const int id = blockIdx.x;
    const int xcd = id & 7, lp = id >> 3;
    const int panel = xcd * 8 + (lp & 7);
    const int bgroup = lp >> 3;
    const int orow0 = panel * 64;

    // per-wave batch and B base (frag-ordered tiles)
    const int batch = bgroup * 4 + wv;
    const char* bW = wsB + (size_t)batch * NT * 8192;

    // A loader: row = tid>>2, 16 floats at slot*(16)
    const int arow = tid >> 2, aslot = tid & 3;
    const float* aSrc = W + (size_t)(orow0 + arow) * K + aslot * 16;
    const int aw0 = aoff(arow, aslot * 2);
    const int aw1 = aoff(arow, aslot * 2 + 1);
    char* const ab0 = lds;
    char* const ab1 = lds + 8192;

    const f32x4 z = {0.f, 0.f, 0.f, 0.f};
    f32x4 acc[4][4];
    #pragma unroll
    for (int m = 0; m < 4; ++m)
        #pragma unroll
        for (int n = 0; n < 4; ++n) acc[m][n] = z;

    float4 aR0[4], aR1[4];
    bf16x8 bR0[8], bR1[8];

    // ---------- prologue ----------
    LOADA(aR0, 0); LOADA(aR1, 1);
    LOADB(bR0, 0); LOADB(bR1, 1);
    asm volatile("s_waitcnt vmcnt(8)" ::: "memory");   // A0,A1,B0 done; B1 in flight
    *(bf16x8*)(ab0 + aw0) = cvt8(aR0[0], aR0[1]);
    *(bf16x8*)(ab0 + aw1) = cvt8(aR0[2], aR0[3]);
    asm volatile("s_waitcnt lgkmcnt(0)" ::: "memory");
    BAR();

    // ---------- main loop (unroll 2, static reg sets) ----------
    for (int t = 0; t < NT; t += 2) {
        // even iter: consume Abuf0/bR0
        if (t + 2 < NT) LOADA(aR0, t + 2);
        MFMAS(ab0, bR0);
        if (t + 2 < NT) LOADB(bR0, t + 2);
        if (t + 2 < NT) asm volatile("s_waitcnt vmcnt(12)" ::: "memory");
        else            asm volatile("s_waitcnt vmcnt(0)" ::: "memory");
        *(bf16x8*)(ab1 + aw0) = cvt8(aR1[0], aR1[1]);       // write A(t+1)
        *(bf16x8*)(ab1 + aw1) = cvt8(aR1[2], aR1[3]);
        asm volatile("s_waitcnt lgkmcnt(0)" ::: "memory");
        BAR();
        // odd iter: consume Abuf1/bR1
        if (t + 3 < NT) LOADA(aR1, t + 3);
        MFMAS(ab1, bR1);
        if (t + 3 < NT) LOADB(bR1, t + 3);
        if (t + 3 < NT) asm volatile("s_waitcnt vmcnt(12)" ::: "memory");
        else            asm volatile("s_waitcnt vmcnt(0)" ::: "memory");
        if (t + 2 < NT) {
            *(bf16x8*)(ab0 + aw0) = cvt8(aR0[0], aR0[1]);   // write A(t+2)
            *(bf16x8*)(ab0 + aw1) = cvt8(aR0[2], aR0[3]);
        }
        asm volatile("s_waitcnt lgkmcnt(0)" ::: "memory");
        BAR();
    }
    __syncthreads();

    // ---------- dump pre+bias -> per-batch [64][64] bf16 swizzled ----------
    {
        char* dst = (wv < 2) ? (preE + wv * 8192) : (hold + (wv - 2) * 8192);
        #pragma unroll
        for (int m = 0; m < 4; ++m)
            #pragma unroll
            for (int n = 0; n < 4; ++n) {
                const int col = n * 16 + lr;
                #pragma unroll
                for (int r = 0; r < 4; ++r) {
                    const int row = m * 16 + lg * 4 + r;
                    const float bs = bias[orow0 + row];
                    *(__bf16*)(dst + row * 128 + ((2 * col) ^ ((row & 7) << 4))) =
                        bfc(acc[m][n][r] + bs);
                }
            }
    }
    __syncthreads();

    // ---------- epilogue: 2 passes x 128 rows (2 batches) ----------
    const int wm = wv >> 1, wn = wv & 1;   // epilogue wave mapping
    #pragma unroll
    for (int p = 0; p < 2; ++p) {
        char* const preB = (p == 0) ? preE : hold;

        // T = relu(info @ fc1W^T + fc1b) -> T_lds [128][64] swizzled
        {
            const int row = tid >> 1;                 // 0..127
            const int j0 = (tid & 1) * 32;
            const int bb = bgroup * 4 + p * 2 + (row >> 6);
            const int g = bb * DOUT + orow0 + (row & 63);
            const float lv = lb[g], uv = ub[g];
            const float lt = fminf(lv, 0.f), ut = fmaxf(uv, 0.f);
            const float diff = ut - lt;
            const float urr = ut / (diff + 1e-8f);
            const float lrr = 1.f - urr, i3 = ps[g], i4 = ss[g];
            #pragma unroll
            for (int c = 0; c < 4; ++c) {
                bf16x8 v;
                #pragma unroll
                for (int jj = 0; jj < 8; ++jj) {
                    const int j = j0 + c * 8 + jj;
                    const float* w = fc1W + j * 5;
                    const float tv = fc1b[j] + urr * w[0] + lrr * w[1] + diff * w[2]
                                   + i3 * w[3] + i4 * w[4];
                    v[jj] = bfc(fmaxf(tv, 0.f));
                }
                *(bf16x8*)(T_lds + aoff(row, (j0 >> 3) + c)) = v;
            }
        }
        __syncthreads();

        // H = T @ fc11W^T + fc11b -> per-batch H tiles
        {
            f32x4 hacc[4][2];
            #pragma unroll
            for (int m = 0; m < 4; ++m) { hacc[m][0] = z; hacc[m][1] = z; }
            #pragma unroll
            for (int ks = 0; ks < 2; ++ks) {
                bf16x8 a[4];
                #pragma unroll
                for (int m = 0; m < 4; ++m)
                    a[m] = *(const bf16x8*)(T_lds + aoff(wm * 64 + m * 16 + lr, ks * 4 + lg));
                #pragma unroll
                for (int n = 0; n < 2; ++n) {
                    const int j = wn * 32 + n * 16 + lr;
                    const bf16x8 bw = *(const bf16x8*)(fc11bf + (size_t)j * 64 + ks * 32 + lg * 8);
                    #pragma unroll
                    for (int m = 0; m < 4; ++m)
                        hacc[m][n] = __builtin_amdgcn_mfma_f32_16x16x32_bf16(a[m], bw, hacc[m][n], 0, 0, 0);
                }
            }
            char* const Hq = H_lds + wm * 8192;
            #pragma unroll
            for (int n = 0; n < 2; ++n) {
                const int j = wn * 32 + n * 16 + lr;
                const float bj = fc11b[j];
                #pragma unroll
                for (int m = 0; m < 4; ++m)
                    #pragma unroll
                    for (int r = 0; r < 4; ++r) {
                        const int row = m * 16 + lg * 4 + r;   // local 0..63
                        *(__bf16*)(Hq + row * 128 + ((2 * j) ^ ((row & 7) << 4))) =
                            bfc(hacc[m][n][r] + bj);
                    }
            }
        }
        __syncthreads();

        // U = relu([pre|H] @ fc2W^T + fc2b) -> T_lds (T dead)
        {
            f32x4 uacc[4][2];
            #pragma unroll
            for (int m = 0; m < 4; ++m) { uacc[m][0] = z; uacc[m][1] = z; }
            #pragma unroll
            for (int ks = 0; ks < 4; ++ks) {
                const char* base = ((ks < 2) ? preB : H_lds) + wm * 8192;
                const int kb = ((ks & 1) * 64 + lg * 16);
                bf16x8 a[4];
                #pragma unroll
                for (int m = 0; m < 4; ++m) {
                    const int row = m * 16 + lr;
                    a[m] = *(const bf16x8*)(base + row * 128 + (kb ^ ((row & 7) << 4)));
                }
                #pragma unroll
                for (int n = 0; n < 2; ++n) {
                    const int j = wn * 32 + n * 16 + lr;
                    const bf16x8 bw = *(const bf16x8*)(fc2bf + (size_t)j * 128 + ks * 32 + lg * 8);
                    #pragma unroll
                    for (int m = 0; m < 4; ++m)
                        uacc[m][n] = __builtin_amdgcn_mfma_f32_16x16x32_bf16(a[m], bw, uacc[m][n], 0, 0, 0);
                }
            }
            __syncthreads();
            #pragma unroll
            for (int n = 0; n < 2; ++n) {
                const int j = wn * 32 + n * 16 + lr;
                const float bj = fc2b[j];
                #pragma unroll
                for (int m = 0; m < 4; ++m)
                    #pragma unroll
                    for (int r = 0; r < 4; ++r) {
                        const int row = wm * 64 + m * 16 + lg * 4 + r;   // 0..127
                        *(__bf16*)(T_lds + row * 128 + ((2 * j) ^ ((row & 7) << 4))) =
                            bfc(fmaxf(uacc[m][n][r] + bj, 0.f));
                    }
            }
        }
        __syncthreads();

        // out = (U @ fc21W^T + fc21b) * mask ; WT staging
        {
            f32x4 oacc[4][2];
            #pragma unroll
            for (int m = 0; m < 4; ++m) { oacc[m][0] = z; oacc[m][1] = z; }
            #pragma unroll
            for (int ks = 0; ks < 2; ++ks) {
                bf16x8 a[4];
                #pragma unroll
                for (int m = 0; m < 4; ++m)
                    a[m] = *(const bf16x8*)(T_lds + aoff(wm * 64 + m * 16 + lr, ks * 4 + lg));
                #pragma unroll
                for (int n = 0; n < 2; ++n) {
                    const int j = wn * 32 + n * 16 + lr;
                    const bf16x8 bw = *(const bf16x8*)(fc21bf + (size_t)j * 64 + ks * 32 + lg * 8);
                    #pragma unroll
                    for (int m = 0; m < 4; ++m)
                        oacc[m][n] = __builtin_amdgcn_mfma_f32_16x16x32_bf16(a[m], bw, oacc[m][n], 0, 0, 0);
                }
            }
            const int bb = bgroup * 4 + p * 2 + wm;
            #pragma unroll
            for (int n = 0; n < 2; ++n) {
                const int j = wn * 32 + n * 16 + lr;
                const float bj = fc21b[j];
                #pragma unroll
                for (int m = 0; m < 4; ++m)
                    #pragma unroll
                    for (int r = 0; r < 4; ++r) {
                        const int row = m * 16 + lg * 4 + r;    // local 0..63
                        const int g = bb * DOUT + orow0 + row;
                        const float o = (oacc[m][n][r] + bj) * mask[g];
                        out[(size_t)g * 64 + j] = o;
                        if (WRITE_T)   // stage transposed [j][row] into preE region
                            *(__bf16*)(preE + wm * 8192 + j * 128 +
                                       ((2 * row) ^ ((j & 7) << 4))) = bfc(o);
                    }
            }
        }
        if (WRITE_T) {
            __syncthreads();
            // emit frag-ordered tiles: 2 batches x 512 chunks
            #pragma unroll
            for (int i = 0; i < 4; ++i) {
                const int idx = i * 256 + tid;          // 0..1023
                const int qq = idx >> 9, rr = idx & 511;
                const int ks = rr >> 8, n = (rr >> 6) & 3, ln = rr & 63;
                const int j = n * 16 + (ln & 15);
                const int k = ks * 32 + (ln >> 4) * 8;
                const bf16x8 v = *(const bf16x8*)(preE + qq * 8192 + j * 128 +
                                                  ((2 * k) ^ ((j & 7) << 4)));
                const int bb = bgroup * 4 + p * 2 + qq;
                *(bf16x8*)(wsT + ((size_t)bb * 64 + panel) * 8192 +
                           ks * 4096 + n * 1024 + ln * 16) = v;
            }
        }
        __syncthreads();
    }
}

extern "C" void kernel_launch(void* const* d_in, const int* in_sizes, int n_in,
                              void* d_out, int out_size, void* d_ws, size_t ws_size,
                              hipStream_t stream) {
    const float* mu0   = (const float*)d_in[0];
    const float* lb1   = (const float*)d_in[1];
    const float* ub1   = (const float*)d_in[2];
    const float* lb2   = (const float*)d_in[3];
    const float* ub2   = (const float*)d_in[4];
    const float* ps1   = (const float*)d_in[5];
    const float* ss1   = (const float*)d_in[6];
    const float* ps2   = (const float*)d_in[7];
    const float* ss2   = (const float*)d_in[8];
    const float* mask1 = (const float*)d_in[9];
    const float* mask2 = (const float*)d_in[10];
    const float* W1    = (const float*)d_in[11];
    const float* b1    = (const float*)d_in[12];
    const float* W2    = (const float*)d_in[13];
    const float* b2    = (const float*)d_in[14];
    const float* fc1W  = (const float*)d_in[15];
    const float* fc1b  = (const float*)d_in[16];
    const float* fc11W = (const float*)d_in[17];
    const float* fc11b = (const float*)d_in[18];
    const float* fc2W  = (const float*)d_in[19];
    const float* fc2b  = (const float*)d_in[20];
    const float* fc21W = (const float*)d_in[21];
    const float* fc21b = (const float*)d_in[22];

    char* ws = (char*)d_ws;
    float* mu1 = (float*)d_out;
    float* mu2 = (float*)d_out + (size_t)16 * 4096 * 64;
    const __bf16* fc11bf = (const __bf16*)(ws + WS_SM);
    const __bf16* fc2bf  = (const __bf16*)(ws + WS_SM) + 4096;
    const __bf16* fc21bf = (const __bf16*)(ws + WS_SM) + 12288;

    prepass_kernel<<<576, 256, 0, stream>>>(mu0, fc11W, fc2W, fc21W, ws);

    layer_kernel<2048, true><<<256, 256, 0, stream>>>(
        W1, b1, ws + WS_MU0, lb1, ub1, ps1, ss1, mask1,
        fc1W, fc1b, fc11bf, fc11b, fc2bf, fc2b, fc21bf, fc21b,
        mu1, ws + WS_MU1);

    layer_kernel<4096, false><<<256, 256, 0, stream>>>(
        W2, b2, ws + WS_MU1, lb2, ub2, ps2, ss2, mask2,
        fc1W, fc1b, fc11bf, fc11b, fc2bf, fc2b, fc21bf, fc21b,
        mu2, nullptr);
}

// Round 8
// 118.102 us; speedup vs baseline: 3.2776x; 1.0671x over previous
//
#include <hip/hip_runtime.h>
#include <hip/hip_bf16.h>

// EmbedLayerUpdate, round 8.
// Block = 64 rows x 128 cols (2 batches), 4 waves = (k-half, batch), each wave
// 64x64 over half the K range -> 2048 waves (2/SIMD), 512 blocks (2/CU).
// B = frag-ordered bf16 in ws, global->VGPR. A = fp32->cvt->swizzled LDS dbuf.
// 1 s_barrier/iter + counted vmcnt(8). K-halves reduced via LDS, then
// round-7 epilogue on 128 rows. B=16, P=64, DOUT=4096.

#define DOUT 4096
typedef __bf16 bf16x8 __attribute__((ext_vector_type(8)));
typedef float  f32x4  __attribute__((ext_vector_type(4)));

__device__ __forceinline__ __bf16 bfc(float x) { return (__bf16)x; }

__device__ __forceinline__ bf16x8 cvt8(const float4 a, const float4 b) {
    bf16x8 r;
    r[0]=bfc(a.x); r[1]=bfc(a.y); r[2]=bfc(a.z); r[3]=bfc(a.w);
    r[4]=bfc(b.x); r[5]=bfc(b.y); r[6]=bfc(b.z); r[7]=bfc(b.w);
    return r;
}

// 128-byte rows (64 bf16): XOR-swizzle 16B chunks with row&7
__device__ __forceinline__ int aoff(int r, int c16) {
    return (r << 7) + ((c16 << 4) ^ ((r & 7) << 4));
}

#define WS_MU0 0
#define WS_MU1 (4u << 20)
#define WS_SM  (12u << 20)

#define BAR() asm volatile("s_barrier" ::: "memory")

// ---- prepass: mu0 -> frag-ordered bf16 tiles; small weights -> bf16 ----
// Tile (8KB) per (batch, kt): chunk(ks,n,lane) 16B holds
// mu[b][kt*64 + ks*32 + (lane>>4)*8 + e][n*16 + (lane&15)], e=0..7.
__global__ __launch_bounds__(256)
void prepass_kernel(const float* __restrict__ mu0, const float* __restrict__ fc11W,
                    const float* __restrict__ fc2W, const float* __restrict__ fc21W,
                    char* __restrict__ ws)
{
    const int blk = blockIdx.x, t = threadIdx.x;
    if (blk < 512) {
        const int b = blk >> 5, kt = blk & 31;
        const int p = t & 63, kc = t >> 6;       // kc 0..3: 16 k each
        const float* src = mu0 + ((size_t)b * 2048 + kt * 64 + kc * 16) * 64 + p;
        char* tile = ws + WS_MU0 + ((size_t)b * 32 + kt) * 8192;
        float v[16];
        #pragma unroll
        for (int i = 0; i < 16; ++i) v[i] = src[(size_t)i * 64];
        bf16x8 o0, o1;
        #pragma unroll
        for (int i = 0; i < 8; ++i) { o0[i] = bfc(v[i]); o1[i] = bfc(v[8 + i]); }
        const int n = p >> 4, ks = kc >> 1;
        const int l0 = (((kc & 1) * 2) << 4) | (p & 15);
        const int l1 = (((kc & 1) * 2 + 1) << 4) | (p & 15);
        *(bf16x8*)(tile + ks * 4096 + n * 1024 + l0 * 16) = o0;
        *(bf16x8*)(tile + ks * 4096 + n * 1024 + l1 * 16) = o1;
    } else {
        const int idx = (blk - 512) * 256 + t;
        __bf16* dst = (__bf16*)(ws + WS_SM);
        if (idx < 4096)        dst[idx] = bfc(fc11W[idx]);
        else if (idx < 12288)  dst[idx] = bfc(fc2W[idx - 4096]);
        else                   dst[idx] = bfc(fc21W[idx - 12288]);
    }
}

#define LOADA(dst, t_) { const float* s_ = aSrc + (size_t)(t_) * 64;            \
    dst[0] = *(const float4*)s_;       dst[1] = *(const float4*)(s_ + 4);       \
    dst[2] = *(const float4*)(s_ + 8); dst[3] = *(const float4*)(s_ + 12); }

#define LOADB(dst, t_) { const char* bp_ = bW + (size_t)(t_) * 8192 + lane * 16; \
    _Pragma("unroll")                                                            \
    for (int n_ = 0; n_ < 4; ++n_) dst[n_] = *(const bf16x8*)(bp_ + n_ * 1024); }

#define MFMAS(Abuf, bset) {                                                      \
    bf16x8 af_[4];                                                               \
    _Pragma("unroll")                                                            \
    for (int m_ = 0; m_ < 4; ++m_)                                               \
        af_[m_] = *(const bf16x8*)((Abuf) + aoff(m_ * 16 + lr, khc + lg));       \
    __builtin_amdgcn_s_setprio(1);                                               \
    _Pragma("unroll")                                                            \
    for (int m_ = 0; m_ < 4; ++m_)                                               \
        _Pragma("unroll")                                                        \
        for (int n_ = 0; n_ < 4; ++n_)                                           \
            acc[m_][n_] = __builtin_amdgcn_mfma_f32_16x16x32_bf16(               \
                af_[m_], bset[n_], acc[m_][n_], 0, 0, 0);                        \
    __builtin_amdgcn_s_setprio(0); }

// ---------------- layer kernel ----------------
template <int K, bool WRITE_T>
__global__ __launch_bounds__(256, 2)
void layer_kernel(const float* __restrict__ W, const float* __restrict__ bias,
                  const char* __restrict__ wsB,
                  const float* __restrict__ lb, const float* __restrict__ ub,
                  const float* __restrict__ ps, const float* __restrict__ ss,
                  const float* __restrict__ mask,
                  const float* __restrict__ fc1W, const float* __restrict__ fc1b,
                  const __bf16* __restrict__ fc11bf, const float* __restrict__ fc11b,
                  const __bf16* __restrict__ fc2bf, const float* __restrict__ fc2b,
                  const __bf16* __restrict__ fc21bf, const float* __restrict__ fc21b,
                  float* __restrict__ out, char* __restrict__ wsT)
{
    constexpr int NT = K / 64;
    __shared__ __align__(16) char lds[49152];
    // main: A dbuf @0/8K. post-loop: red @0..32K; pre @32K..48K;
    // T @0..16K; H @16K..32K; U -> T region; WT staging -> H region.
    char* const pre   = lds + 32768;
    char* const T_lds = lds;
    char* const H_lds = lds + 16384;

    const int tid = threadIdx.x;
    const int lane = tid & 63, wv = tid >> 6;
    const int kh = wv >> 1, bn = wv & 1;         // k-half, batch-in-block
    const int khc = kh * 4;
    const int lr = lane & 15, lg = lane >> 4;

    // XCD swizzle: 512 = 8 xcd * 64; XCD gets 8 panels x 8 bgroups
    const int id = blockIdx.x;
    const int vid = (id & 7) * 64 + (id >> 3);
    const int panel = vid >> 3;                  // 0..63 (64-row panels)
    const int bgroup = vid & 7;                  // 0..7 (2 batches each)
    const int orow0 = panel * 64;
    const int batch0 = bgroup * 2;

    const char* bW = wsB + ((size_t)(batch0 + bn) * NT) * 8192 + khc * 1024;

    // A loader: row = tid>>2, slot = tid&3 (16 floats = 64B contiguous)
    const int arow = tid >> 2, aslot = tid & 3;
    const float* aSrc = W + (size_t)(orow0 + arow) * K + aslot * 16;
    const int aw0 = aoff(arow, aslot * 2);
    const int aw1 = aoff(arow, aslot * 2 + 1);
    char* const ab0 = lds;
    char* const ab1 = lds + 8192;

    const f32x4 z = {0.f, 0.f, 0.f, 0.f};
    f32x4 acc[4][4];
    #pragma unroll
    for (int m = 0; m < 4; ++m)
        #pragma unroll
        for (int n = 0; n < 4; ++n) acc[m][n] = z;

    float4 aR0[4], aR1[4];
    bf16x8 bR0[4], bR1[4];

    // ---------- prologue ----------
    LOADA(aR0, 0); LOADB(bR0, 0);
    LOADA(aR1, 1); LOADB(bR1, 1);
    asm volatile("s_waitcnt vmcnt(8)" ::: "memory");   // aR0,bR0 done
    *(bf16x8*)(ab0 + aw0) = cvt8(aR0[0], aR0[1]);
    *(bf16x8*)(ab0 + aw1) = cvt8(aR0[2], aR0[3]);
    asm volatile("s_waitcnt lgkmcnt(0)" ::: "memory");
    BAR();

    // ---------- main loop (unroll 2, static reg sets) ----------
    for (int t = 0; t < NT; t += 2) {
        // even: consume ab0/bR0
        if (t + 2 < NT) LOADA(aR0, t + 2);
        MFMAS(ab0, bR0);
        if (t + 2 < NT) LOADB(bR0, t + 2);
        if (t + 2 < NT) asm volatile("s_waitcnt vmcnt(8)" ::: "memory");
        else            asm volatile("s_waitcnt vmcnt(0)" ::: "memory");
        *(bf16x8*)(ab1 + aw0) = cvt8(aR1[0], aR1[1]);   // A(t+1)
        *(bf16x8*)(ab1 + aw1) = cvt8(aR1[2], aR1[3]);
        asm volatile("s_waitcnt lgkmcnt(0)" ::: "memory");
        BAR();
        // odd: consume ab1/bR1
        if (t + 3 < NT) LOADA(aR1, t + 3);
        MFMAS(ab1, bR1);
        if (t + 3 < NT) LOADB(bR1, t + 3);
        if (t + 3 < NT) asm volatile("s_waitcnt vmcnt(8)" ::: "memory");
        else            asm volatile("s_waitcnt vmcnt(0)" ::: "memory");
        if (t + 2 < NT) {
            *(bf16x8*)(ab0 + aw0) = cvt8(aR0[0], aR0[1]);   // A(t+2)
            *(bf16x8*)(ab0 + aw1) = cvt8(aR0[2], aR0[3]);
        }
        asm volatile("s_waitcnt lgkmcnt(0)" ::: "memory");
        BAR();
    }
    __syncthreads();

    // ---------- k-half reduction; pre+bias -> per-batch [64][64] bf16 ----------
    if (kh == 0) {
        #pragma unroll
        for (int m = 0; m < 4; ++m)
            #pragma unroll
            for (int n = 0; n < 4; ++n)
                *(f32x4*)(lds + bn * 16384 + ((m * 4 + n) * 64 + lane) * 16) = acc[m][n];
    }
    __syncthreads();
    if (kh == 1) {
        #pragma unroll
        for (int m = 0; m < 4; ++m)
            #pragma unroll
            for (int n = 0; n < 4; ++n)
                acc[m][n] += *(const f32x4*)(lds + bn * 16384 + ((m * 4 + n) * 64 + lane) * 16);
        char* const dst = pre + bn * 8192;
        #pragma unroll
        for (int m = 0; m < 4; ++m)
            #pragma unroll
            for (int n = 0; n < 4; ++n) {
                const int col = n * 16 + lr;
                #pragma unroll
                for (int r = 0; r < 4; ++r) {
                    const int row = m * 16 + lg * 4 + r;
                    const float bs = bias[orow0 + row];
                    *(__bf16*)(dst + row * 128 + ((2 * col) ^ ((row & 7) << 4))) =
                        bfc(acc[m][n][r] + bs);
                }
            }
    }
    __syncthreads();

    // ---------- epilogue on 128 rows (2 batches x 64) ----------
    const int wm = wv >> 1, wn = wv & 1;

    // T = relu(info @ fc1W^T + fc1b) -> T_lds [128][64] swizzled
    {
        const int row = tid >> 1;                 // 0..127
        const int j0 = (tid & 1) * 32;
        const int bb = batch0 + (row >> 6);
        const int g = bb * DOUT + orow0 + (row & 63);
        const float lv = lb[g], uv = ub[g];
        const float lt = fminf(lv, 0.f), ut = fmaxf(uv, 0.f);
        const float diff = ut - lt;
        const float urr = ut / (diff + 1e-8f);
        const float lrr = 1.f - urr, i3 = ps[g], i4 = ss[g];
        #pragma unroll
        for (int c = 0; c < 4; ++c) {
            bf16x8 v;
            #pragma unroll
            for (int jj = 0; jj < 8; ++jj) {
                const int j = j0 + c * 8 + jj;
                const float* w = fc1W + j * 5;
                const float tv = fc1b[j] + urr * w[0] + lrr * w[1] + diff * w[2]
                               + i3 * w[3] + i4 * w[4];
                v[jj] = bfc(fmaxf(tv, 0.f));
            }
            *(bf16x8*)(T_lds + aoff(row, (j0 >> 3) + c)) = v;
        }
    }
    __syncthreads();

    // H = T @ fc11W^T + fc11b -> per-batch H tiles
    {
        f32x4 hacc[4][2];
        #pragma unroll
        for (int m = 0; m < 4; ++m) { hacc[m][0] = z; hacc[m][1] = z; }
        #pragma unroll
        for (int ks = 0; ks < 2; ++ks) {
            bf16x8 a[4];
            #pragma unroll
            for (int m = 0; m < 4; ++m)
                a[m] = *(const bf16x8*)(T_lds + aoff(wm * 64 + m * 16 + lr, ks * 4 + lg));
            #pragma unroll
            for (int n = 0; n < 2; ++n) {
                const int j = wn * 32 + n * 16 + lr;
                const bf16x8 bw = *(const bf16x8*)(fc11bf + (size_t)j * 64 + ks * 32 + lg * 8);
                #pragma unroll
                for (int m = 0; m < 4; ++m)
                    hacc[m][n] = __builtin_amdgcn_mfma_f32_16x16x32_bf16(a[m], bw, hacc[m][n], 0, 0, 0);
            }
        }
        char* const Hq = H_lds + wm * 8192;
        #pragma unroll
        for (int n = 0; n < 2; ++n) {
            const int j = wn * 32 + n * 16 + lr;
            const float bj = fc11b[j];
            #pragma unroll
            for (int m = 0; m < 4; ++m)
                #pragma unroll
                for (int r = 0; r < 4; ++r) {
                    const int row = m * 16 + lg * 4 + r;   // local 0..63
                    *(__bf16*)(Hq + row * 128 + ((2 * j) ^ ((row & 7) << 4))) =
                        bfc(hacc[m][n][r] + bj);
                }
        }
    }
    __syncthreads();

    // U = relu([pre|H] @ fc2W^T + fc2b) -> T region (T dead)
    {
        f32x4 uacc[4][2];
        #pragma unroll
        for (int m = 0; m < 4; ++m) { uacc[m][0] = z; uacc[m][1] = z; }
        #pragma unroll
        for (int ks = 0; ks < 4; ++ks) {
            const char* base = ((ks < 2) ? pre : H_lds) + wm * 8192;
            const int kb = ((ks & 1) * 64 + lg * 16);
            bf16x8 a[4];
            #pragma unroll
            for (int m = 0; m < 4; ++m) {
                const int row = m * 16 + lr;
                a[m] = *(const bf16x8*)(base + row * 128 + (kb ^ ((row & 7) << 4)));
            }
            #pragma unroll
            for (int n = 0; n < 2; ++n) {
                const int j = wn * 32 + n * 16 + lr;
                const bf16x8 bw = *(const bf16x8*)(fc2bf + (size_t)j * 128 + ks * 32 + lg * 8);
                #pragma unroll
                for (int m = 0; m < 4; ++m)
                    uacc[m][n] = __builtin_amdgcn_mfma_f32_16x16x32_bf16(a[m], bw, uacc[m][n], 0, 0, 0);
            }
        }
        __syncthreads();
        #pragma unroll
        for (int n = 0; n < 2; ++n) {
            const int j = wn * 32 + n * 16 + lr;
            const float bj = fc2b[j];
            #pragma unroll
            for (int m = 0; m < 4; ++m)
                #pragma unroll
                for (int r = 0; r < 4; ++r) {
                    const int row = wm * 64 + m * 16 + lg * 4 + r;   // 0..127
                    *(__bf16*)(T_lds + row * 128 + ((2 * j) ^ ((row & 7) << 4))) =
                        bfc(fmaxf(uacc[m][n][r] + bj, 0.f));
                }
        }
    }
    __syncthreads();

    // out = (U @ fc21W^T + fc21b) * mask ; WT staging -> H region
    {
        f32x4 oacc[4][2];
        #pragma unroll
        for (int m = 0; m < 4; ++m) { oacc[m][0] = z; oacc[m][1] = z; }
        #pragma unroll
        for (int ks = 0; ks < 2; ++ks) {
            bf16x8 a[4];
            #pragma unroll
            for (int m = 0; m < 4; ++m)
                a[m] = *(const bf16x8*)(T_lds + aoff(wm * 64 + m * 16 + lr, ks * 4 + lg));
            #pragma unroll
            for (int n = 0; n < 2; ++n) {
                const int j = wn * 32 + n * 16 + lr;
                const bf16x8 bw = *(const bf16x8*)(fc21bf + (size_t)j * 64 + ks * 32 + lg * 8);
                #pragma unroll
                for (int m = 0; m < 4; ++m)
                    oacc[m][n] = __builtin_amdgcn_mfma_f32_16x16x32_bf16(a[m], bw, oacc[m][n], 0, 0, 0);
            }
        }
        const int bb = batch0 + wm;
        #pragma unroll
        for (int n = 0; n < 2; ++n) {
            const int j = wn * 32 + n * 16 + lr;
            const float bj = fc21b[j];
            #pragma unroll
            for (int m = 0; m < 4; ++m)
                #pragma unroll
                for (int r = 0; r < 4; ++r) {
                    const int row = m * 16 + lg * 4 + r;    // local 0..63
                    const int g = bb * DOUT + orow0 + row;
                    const float o = (oacc[m][n][r] + bj) * mask[g];
                    out[(size_t)g * 64 + j] = o;
                    if (WRITE_T)
                        *(__bf16*)(H_lds + wm * 8192 + j * 128 +
                                   ((2 * row) ^ ((j & 7) << 4))) = bfc(o);
                }
        }
    }
    if (WRITE_T) {
        __syncthreads();
        // emit frag-ordered tiles: 2 batches x 512 chunks
        #pragma unroll
        for (int i = 0; i < 4; ++i) {
            const int idx = i * 256 + tid;          // 0..1023
            const int qq = idx >> 9, rr = idx & 511;
            const int ks = rr >> 8, n = (rr >> 6) & 3, ln = rr & 63;
            const int j = n * 16 + (ln & 15);
            const int k = ks * 32 + (ln >> 4) * 8;
            const bf16x8 v = *(const bf16x8*)(H_lds + qq * 8192 + j * 128 +
                                              ((2 * k) ^ ((j & 7) << 4)));
            const int bb = batch0 + qq;
            *(bf16x8*)(wsT + ((size_t)bb * 64 + panel) * 8192 +
                       ks * 4096 + n * 1024 + ln * 16) = v;
        }
    }
}

extern "C" void kernel_launch(void* const* d_in, const int* in_sizes, int n_in,
                              void* d_out, int out_size, void* d_ws, size_t ws_size,
                              hipStream_t stream) {
    const float* mu0   = (const float*)d_in[0];
    const float* lb1   = (const float*)d_in[1];
    const float* ub1   = (const float*)d_in[2];
    const float* lb2   = (const float*)d_in[3];
    const float* ub2   = (const float*)d_in[4];
    const float* ps1   = (const float*)d_in[5];
    const float* ss1   = (const float*)d_in[6];
    const float* ps2   = (const float*)d_in[7];
    const float* ss2   = (const float*)d_in[8];
    const float* mask1 = (const float*)d_in[9];
    const float* mask2 = (const float*)d_in[10];
    const float* W1    = (const float*)d_in[11];
    const float* b1    = (const float*)d_in[12];
    const float* W2    = (const float*)d_in[13];
    const float* b2    = (const float*)d_in[14];
    const float* fc1W  = (const float*)d_in[15];
    const float* fc1b  = (const float*)d_in[16];
    const float* fc11W = (const float*)d_in[17];
    const float* fc11b = (const float*)d_in[18];
    const float* fc2W  = (const float*)d_in[19];
    const float* fc2b  = (const float*)d_in[20];
    const float* fc21W = (const float*)d_in[21];
    const float* fc21b = (const float*)d_in[22];

    char* ws = (char*)d_ws;
    float* mu1 = (float*)d_out;
    float* mu2 = (float*)d_out + (size_t)16 * 4096 * 64;
    const __bf16* fc11bf = (const __bf16*)(ws + WS_SM);
    const __bf16* fc2bf  = (const __bf16*)(ws + WS_SM) + 4096;
    const __bf16* fc21bf = (const __bf16*)(ws + WS_SM) + 12288;

    prepass_kernel<<<576, 256, 0, stream>>>(mu0, fc11W, fc2W, fc21W, ws);

    layer_kernel<2048, true><<<512, 256, 0, stream>>>(
        W1, b1, ws + WS_MU0, lb1, ub1, ps1, ss1, mask1,
        fc1W, fc1b, fc11bf, fc11b, fc2bf, fc2b, fc21bf, fc21b,
        mu1, ws + WS_MU1);

    layer_kernel<4096, false><<<512, 256, 0, stream>>>(
        W2, b2, ws + WS_MU1, lb2, ub2, ps2, ss2, mask2,
        fc1W, fc1b, fc11bf, fc11b, fc2bf, fc2b, fc21bf, fc21b,
        mu2, nullptr);
}